// Round 2
// baseline (450.339 us; speedup 1.0000x reference)
//
#include <hip/hip_runtime.h>
#include <math.h>

#define NU 200000
#define NI 100000
#define NN 300000
#define DD 64
#define EDGES 1000000
#define E2 2000000
#define BATCH 4096
#define SCAN_CHUNK 1024
#define NBLK1 ((NN + SCAN_CHUNK - 1) / SCAN_CHUNK)   // 293
#define FIX_SCALE 131072.0f                           // 2^17
#define FIX_INV   7.62939453125e-06f                  // 2^-17

#define MLP_BLOCKS2 ((E2 + 511) / 512)   // 3907 (2 edges/thread, 512 edges/block)
#define FUSE_BLOCKS4 (NI / 16)           // 6250 (16 items/block, 4 per wave)
#define COPY_BLOCKS (NU * DD / 4 / 256)  // 12500
#define PREP_GRID 25000                  // period-4: {A,B,C,C}

__device__ __forceinline__ unsigned short f2bf(float f) {  // RNE
    unsigned u = __float_as_uint(f);
    return (unsigned short)((u + 0x7fffu + ((u >> 16) & 1u)) >> 16);
}
__device__ __forceinline__ float bflo(unsigned v) { return __uint_as_float(v << 16); }
__device__ __forceinline__ float bfhi(unsigned v) { return __uint_as_float(v & 0xffff0000u); }

// fused prep, period-4 stripe {A,B,C,C}.
// role A: edge MLP -> w, packed u32 deg/count atomic, epos (2 edges/thread,
//         weights read via uniform global loads -> s_load + SGPR fma, NO LDS)
// role B: item fuse + adapter + l2norm -> bf16 x rows [NU, NN) (4 items/wave)
// role C: f32->bf16 copy of user rows [0, NU)
__global__ __launch_bounds__(256) void k_prep(
    const float* __restrict__ ef, const float* __restrict__ W1,
    const float* __restrict__ b1, const float* __restrict__ W2,
    const float* __restrict__ b2, const int* __restrict__ eu,
    const int* __restrict__ ei, float* __restrict__ w,
    unsigned* __restrict__ degc, int* __restrict__ epos,
    const float* __restrict__ item_audio, const float* __restrict__ artist_emb,
    const float* __restrict__ album_emb, const int* __restrict__ artist_ids,
    const int* __restrict__ album_ids, const float* __restrict__ aW,
    const float* __restrict__ ab, const float* __restrict__ user_emb,
    unsigned short* __restrict__ x) {
    __shared__ float4 sW4[64][16];          // role B: adapter, XOR-swizzled (16 KiB)
    __shared__ float4 sv4[16][16];          // role B: fused item vectors (4 KiB)
    int bid = blockIdx.x;
    int tid = threadIdx.x;
    int r = bid & 3, base = bid >> 2;
    if (r == 0) {                               // ---- role A: edge MLP + deg
        if (base >= MLP_BLOCKS2) return;
        int e0 = base * 512 + tid;
        int e1 = e0 + 256;
        int e0c = e0 < E2 ? e0 : 0;             // clamp loads, guard stores
        int e1c = e1 < E2 ? e1 : 0;
        float4 fa0 = ((const float4*)ef)[2 * e0c];
        float4 fa1 = ((const float4*)ef)[2 * e0c + 1];
        float4 fb0 = ((const float4*)ef)[2 * e1c];
        float4 fb1 = ((const float4*)ef)[2 * e1c + 1];
        float z0 = b2[0], z1 = b2[0];           // uniform -> scalar load
#pragma unroll
        for (int i = 0; i < 32; ++i) {
            float4 wa = ((const float4*)W1)[2 * i];      // uniform -> s_load
            float4 wb = ((const float4*)W1)[2 * i + 1];
            float bi = b1[i], wo = W2[i];
            float a0 = bi + fa0.x * wa.x + fa0.y * wa.y + fa0.z * wa.z +
                       fa0.w * wa.w + fa1.x * wb.x + fa1.y * wb.y +
                       fa1.z * wb.z + fa1.w * wb.w;
            float a1 = bi + fb0.x * wa.x + fb0.y * wa.y + fb0.z * wa.z +
                       fb0.w * wa.w + fb1.x * wb.x + fb1.y * wb.y +
                       fb1.z * wb.z + fb1.w * wb.w;
            z0 += wo * fmaxf(a0, 0.0f);
            z1 += wo * fmaxf(a1, 0.0f);
        }
        if (e0 < E2) {
            float we = 1.0f / (1.0f + __expf(-z0));
            w[e0] = we;
            int c = (e0 < EDGES) ? (NU + ei[e0]) : eu[e0 - EDGES];
            unsigned old = atomicAdd(
                &degc[c], (1u << 24) | (unsigned)(we * FIX_SCALE + 0.5f));
            epos[e0] = (int)(old >> 24);
        }
        if (e1 < E2) {
            float we = 1.0f / (1.0f + __expf(-z1));
            w[e1] = we;
            int c = (e1 < EDGES) ? (NU + ei[e1]) : eu[e1 - EDGES];
            unsigned old = atomicAdd(
                &degc[c], (1u << 24) | (unsigned)(we * FIX_SCALE + 0.5f));
            epos[e1] = (int)(old >> 24);
        }
        return;
    }
    if (r == 1) {                               // ---- role B: item fuse
        int j = base;                           // j < 6250 exactly
#pragma unroll
        for (int s = 0; s < 4; ++s) {
            int i4 = tid + s * 256;
            int row = i4 >> 4, c4 = i4 & 15;
            sW4[row][(c4 & 8) | ((c4 ^ row) & 7)] = ((const float4*)aW)[i4];
        }
        __syncthreads();
        int wave = tid >> 6, lane = tid & 63;
        int it0 = j * 16 + wave * 4;            // items it0..it0+3
        float* svf = (float*)sv4;
#pragma unroll
        for (int t = 0; t < 4; ++t) {
            int it = it0 + t;
            int ar = artist_ids[it], al = album_ids[it];
            float v = item_audio[it * DD + lane] + artist_emb[ar * DD + lane] +
                      album_emb[al * DD + lane];
            svf[(wave * 4 + t) * DD + lane] = v;   // same-wave use: no barrier
        }
        float bias = ab[lane];
        float t0 = bias, t1 = bias, t2 = bias, t3 = bias;
#pragma unroll
        for (int k4 = 0; k4 < 16; ++k4) {
            float4 wv = sW4[lane][(k4 & 8) | ((k4 ^ lane) & 7)];
            float4 va = sv4[wave * 4 + 0][k4];  // uniform broadcasts
            float4 vb = sv4[wave * 4 + 1][k4];
            float4 vc = sv4[wave * 4 + 2][k4];
            float4 vd = sv4[wave * 4 + 3][k4];
            t0 += wv.x * va.x + wv.y * va.y + wv.z * va.z + wv.w * va.w;
            t1 += wv.x * vb.x + wv.y * vb.y + wv.z * vb.z + wv.w * vb.w;
            t2 += wv.x * vc.x + wv.y * vc.y + wv.z * vc.z + wv.w * vc.w;
            t3 += wv.x * vd.x + wv.y * vd.y + wv.z * vd.z + wv.w * vd.w;
        }
        float s0 = t0 * t0, s1 = t1 * t1, s2 = t2 * t2, s3 = t3 * t3;
        for (int m = 32; m >= 1; m >>= 1) {
            s0 += __shfl_xor(s0, m, 64);
            s1 += __shfl_xor(s1, m, 64);
            s2 += __shfl_xor(s2, m, 64);
            s3 += __shfl_xor(s3, m, 64);
        }
        x[(NU + it0 + 0) * DD + lane] = f2bf(t0 / fmaxf(sqrtf(s0), 1e-12f));
        x[(NU + it0 + 1) * DD + lane] = f2bf(t1 / fmaxf(sqrtf(s1), 1e-12f));
        x[(NU + it0 + 2) * DD + lane] = f2bf(t2 / fmaxf(sqrtf(s2), 1e-12f));
        x[(NU + it0 + 3) * DD + lane] = f2bf(t3 / fmaxf(sqrtf(s3), 1e-12f));
        return;
    }
    int cb = base * 2 + (r - 2);                // ---- role C: copy users
    int i = cb * 256 + tid;                     // cb < 12500 exactly
    float4 v = ((const float4*)user_emb)[i];
    ushort4 o;
    o.x = f2bf(v.x); o.y = f2bf(v.y); o.z = f2bf(v.z); o.w = f2bf(v.w);
    ((ushort4*)x)[i] = o;
}

// ---- exclusive prefix sum over PADDED counts (ceil(cnt/8)*8) -> rowptr ----
__global__ __launch_bounds__(1024) void k_scan_local(
    const unsigned* __restrict__ degc, int* __restrict__ rowptr,
    int* __restrict__ bsum) {
    __shared__ int sh[SCAN_CHUNK];
    int tid = threadIdx.x;
    int i = blockIdx.x * SCAN_CHUNK + tid;
    int cnt = (i < NN) ? (int)(degc[i] >> 24) : 0;
    int v = (cnt + 7) & ~7;
    sh[tid] = v;
    __syncthreads();
    for (int off = 1; off < SCAN_CHUNK; off <<= 1) {
        int t = (tid >= off) ? sh[tid - off] : 0;
        __syncthreads();
        sh[tid] += t;
        __syncthreads();
    }
    if (i < NN) rowptr[i] = sh[tid] - v;  // exclusive
    if (tid == SCAN_CHUNK - 1) bsum[blockIdx.x] = sh[tid];
}

__global__ __launch_bounds__(512) void k_scan_bsum(int* __restrict__ bsum) {
    __shared__ int sh[512];
    int tid = threadIdx.x;
    int v = (tid < NBLK1) ? bsum[tid] : 0;
    sh[tid] = v;
    __syncthreads();
    for (int off = 1; off < 512; off <<= 1) {
        int t = (tid >= off) ? sh[tid - off] : 0;
        __syncthreads();
        sh[tid] += t;
        __syncthreads();
    }
    if (tid < NBLK1) bsum[tid] = sh[tid] - v;  // exclusive
}

// rowptr += block offsets; dis = rsqrt(degree); zero the pad slots of csre
__global__ void k_scan_add_dis(int* __restrict__ rowptr, const int* __restrict__ bsum,
                               const unsigned* __restrict__ degc,
                               float* __restrict__ dis, int2* __restrict__ csre) {
    int i = blockIdx.x * blockDim.x + threadIdx.x;
    if (i >= NN) return;
    int rp = rowptr[i] + bsum[i >> 10];
    rowptr[i] = rp;
    unsigned dc = degc[i];
    int cnt = (int)(dc >> 24);
    int pcnt = (cnt + 7) & ~7;
    float d = (float)(dc & 0xFFFFFFu) * FIX_INV;
    dis[i] = d > 0.0f ? rsqrtf(d) : 0.0f;
    for (int k = cnt; k < pcnt; ++k) csre[rp + k] = make_int2(0, 0);  // pad: row0,w=0
    if (i == NN - 1) rowptr[NN] = rp + pcnt;
}

// fill CSR: atomic-free; slot = {source row BYTE offset, fused gcn weight}
__global__ void k_fill(const float* __restrict__ w, const int* __restrict__ eu,
                       const int* __restrict__ ei, const float* __restrict__ dis,
                       const int* __restrict__ rowptr, const int* __restrict__ epos,
                       int2* __restrict__ csre) {
    int e = blockIdx.x * blockDim.x + threadIdx.x;
    if (e >= E2) return;
    int r, c;
    if (e < EDGES) { r = eu[e]; c = NU + ei[e]; }
    else           { r = NU + ei[e - EDGES]; c = eu[e - EDGES]; }
    int pos = rowptr[c] + epos[e];
    csre[pos] = make_int2(r * (DD * 2), __float_as_int(dis[r] * w[e] * dis[c]));
}

// mark nodes whose z2 is consumed by the tail (sources of batch-row buckets)
__global__ void k_mark(const int* __restrict__ uidx, const int* __restrict__ pidx,
                       const int* __restrict__ rowptr, const int2* __restrict__ csre,
                       unsigned char* __restrict__ flags) {
    int t = blockIdx.x * blockDim.x + threadIdx.x;
    if (t >= 2 * BATCH) return;
    int row = (t < BATCH) ? uidx[t] : NU + pidx[t - BATCH];
    int beg = rowptr[row], end = rowptr[row + 1];
    for (int e = beg; e < end; ++e) flags[((unsigned)csre[e].x) >> 7] = 1;
}

// quarter-wave pull: 16 lanes cover a row (4 dims each via 8B gather),
// quarter q handles edges e+2q, e+2q+1; csre read as int4 (2 edges/load).
__device__ __forceinline__ void pull4(const char* __restrict__ xb,
                                      const int2* __restrict__ csre,
                                      int beg, int end, int q2, int t8,
                                      float& a0, float& a1, float& a2, float& a3) {
    a0 = a1 = a2 = a3 = 0.0f;
    for (int e = beg; e < end; e += 8) {
        int4 s = *(const int4*)(csre + (e + q2));   // {offA,wA,offB,wB}
        uint2 va = *(const uint2*)(xb + (unsigned)s.x + t8);
        uint2 vb = *(const uint2*)(xb + (unsigned)s.z + t8);
        float wa = __int_as_float(s.y), wb = __int_as_float(s.w);
        a0 = fmaf(bflo(va.x), wa, a0);
        a1 = fmaf(bfhi(va.x), wa, a1);
        a2 = fmaf(bflo(va.y), wa, a2);
        a3 = fmaf(bfhi(va.y), wa, a3);
        a0 = fmaf(bflo(vb.x), wb, a0);
        a1 = fmaf(bfhi(vb.x), wb, a1);
        a2 = fmaf(bflo(vb.y), wb, a2);
        a3 = fmaf(bfhi(vb.y), wb, a3);
    }
    a0 += __shfl_xor(a0, 16, 64); a1 += __shfl_xor(a1, 16, 64);
    a2 += __shfl_xor(a2, 16, 64); a3 += __shfl_xor(a3, 16, 64);
    a0 += __shfl_xor(a0, 32, 64); a1 += __shfl_xor(a1, 32, 64);
    a2 += __shfl_xor(a2, 32, 64); a3 += __shfl_xor(a3, 32, 64);
}

// propagation layer (bf16 -> bf16), one wave per node; FLAGS: skip unmarked
template <bool FLAGS>
__global__ __launch_bounds__(256) void k_prop(
    const unsigned short* __restrict__ x, const int* __restrict__ rowptr,
    const int2* __restrict__ csre, unsigned short* __restrict__ xn,
    const unsigned char* __restrict__ flags) {
    int tid = threadIdx.x;
    int node = blockIdx.x * 4 + (tid >> 6);
    if (node >= NN) return;
    if (FLAGS && !flags[node]) return;
    int lane = tid & 63;
    int q2 = (lane >> 4) << 1;
    int t8 = (lane & 15) * 8;
    float a0, a1, a2, a3;
    pull4((const char*)x, csre, rowptr[node], rowptr[node + 1], q2, t8,
          a0, a1, a2, a3);
    if ((lane >> 4) == 0) {
        unsigned lo = ((unsigned)f2bf(a1) << 16) | (unsigned)f2bf(a0);
        unsigned hi = ((unsigned)f2bf(a3) << 16) | (unsigned)f2bf(a2);
        *(uint2*)((char*)xn + (size_t)node * 128 + t8) = make_uint2(lo, hi);
    }
}

// layer-3 + l2norm + cosine loss, only for the 2*BATCH consumed rows
__global__ __launch_bounds__(256) void k_tail(
    const unsigned short* __restrict__ x, const int* __restrict__ rowptr,
    const int2* __restrict__ csre, const int* __restrict__ uidx,
    const int* __restrict__ pidx, float* __restrict__ out) {
    int tid = threadIdx.x;
    int b = blockIdx.x * 4 + (tid >> 6);
    if (b >= BATCH) return;
    int lane = tid & 63;
    int q2 = (lane >> 4) << 1;
    int t8 = (lane & 15) * 8;
    const char* xb = (const char*)x;
    int un = uidx[b], pn = NU + pidx[b];
    float u0, u1, u2, u3, p0, p1, p2, p3, ss, s;
    pull4(xb, csre, rowptr[un], rowptr[un + 1], q2, t8, u0, u1, u2, u3);
    ss = u0 * u0 + u1 * u1 + u2 * u2 + u3 * u3;
    for (int m = 8; m >= 1; m >>= 1) ss += __shfl_xor(ss, m, 64);
    s = 1.0f / fmaxf(sqrtf(ss), 1e-12f);
    u0 *= s; u1 *= s; u2 *= s; u3 *= s;
    pull4(xb, csre, rowptr[pn], rowptr[pn + 1], q2, t8, p0, p1, p2, p3);
    ss = p0 * p0 + p1 * p1 + p2 * p2 + p3 * p3;
    for (int m = 8; m >= 1; m >>= 1) ss += __shfl_xor(ss, m, 64);
    s = 1.0f / fmaxf(sqrtf(ss), 1e-12f);
    p0 *= s; p1 *= s; p2 *= s; p3 *= s;
    if ((lane >> 4) == 0)
        ((float4*)out)[b * 16 + (t8 >> 3)] = make_float4(u0, u1, u2, u3);
    float dot = u0 * p0 + u1 * p1 + u2 * p2 + u3 * p3;
    float uu = u0 * u0 + u1 * u1 + u2 * u2 + u3 * u3;
    float pp = p0 * p0 + p1 * p1 + p2 * p2 + p3 * p3;
    for (int m = 8; m >= 1; m >>= 1) {
        dot += __shfl_xor(dot, m, 64);
        uu  += __shfl_xor(uu, m, 64);
        pp  += __shfl_xor(pp, m, 64);
    }
    if (lane == 0) {
        float cs = dot / (fmaxf(sqrtf(uu), 1e-8f) * fmaxf(sqrtf(pp), 1e-8f));
        atomicAdd(out + BATCH * DD, (1.0f - cs) * (1.0f / BATCH));
    }
}

extern "C" void kernel_launch(void* const* d_in, const int* in_sizes, int n_in,
                              void* d_out, int out_size, void* d_ws, size_t ws_size,
                              hipStream_t stream) {
    const float* user_emb      = (const float*)d_in[0];
    const float* artist_emb    = (const float*)d_in[1];
    const float* album_emb     = (const float*)d_in[2];
    const float* item_audio    = (const float*)d_in[3];
    const float* adapter_W     = (const float*)d_in[4];
    const float* adapter_b     = (const float*)d_in[5];
    const float* mlp_W1        = (const float*)d_in[6];
    const float* mlp_b1        = (const float*)d_in[7];
    const float* mlp_W2        = (const float*)d_in[8];
    const float* mlp_b2        = (const float*)d_in[9];
    const float* edge_features = (const float*)d_in[10];
    const int*   edge_user     = (const int*)d_in[11];
    const int*   edge_item     = (const int*)d_in[12];
    const int*   artist_ids    = (const int*)d_in[13];
    const int*   album_ids     = (const int*)d_in[14];
    const int*   user_idx      = (const int*)d_in[15];
    const int*   pos_item_id   = (const int*)d_in[16];

    char* p = (char*)d_ws;
    unsigned short* XB0 = (unsigned short*)p; p += (size_t)NN * DD * 2;
    unsigned short* XB1 = (unsigned short*)p; p += (size_t)NN * DD * 2;
    float* W       = (float*)p; p += (size_t)E2 * 4;
    int2*  CSRE    = (int2*)p;  p += (size_t)4200000 * 8;   // padded CSR
    int*   EPOS    = (int*)p;   p += (size_t)E2 * 4;
    unsigned* DEGC = (unsigned*)p; p += (size_t)NN * 8;     // u32 used, u64 reserved
    float* DIS     = (float*)p; p += (size_t)NN * 4;
    int*   ROWPTR  = (int*)p;   p += (size_t)(NN + 1) * 4;
    int*   BSUM    = (int*)p;   p += (size_t)((NBLK1 + 3) & ~3) * 4;
    unsigned char* FLAGS = (unsigned char*)p; p += (size_t)NN;

    hipMemsetAsync(DEGC, 0, NN * sizeof(unsigned), stream);
    hipMemsetAsync(FLAGS, 0, NN, stream);
    hipMemsetAsync((float*)d_out + BATCH * DD, 0, sizeof(float), stream);

    k_prep<<<PREP_GRID, 256, 0, stream>>>(
        edge_features, mlp_W1, mlp_b1, mlp_W2, mlp_b2, edge_user, edge_item,
        W, DEGC, EPOS, item_audio, artist_emb, album_emb, artist_ids, album_ids,
        adapter_W, adapter_b, user_emb, XB0);

    k_scan_local<<<NBLK1, SCAN_CHUNK, 0, stream>>>(DEGC, ROWPTR, BSUM);
    k_scan_bsum<<<1, 512, 0, stream>>>(BSUM);
    k_scan_add_dis<<<(NN + 255) / 256, 256, 0, stream>>>(ROWPTR, BSUM, DEGC, DIS,
                                                         CSRE);
    k_fill<<<(E2 + 255) / 256, 256, 0, stream>>>(W, edge_user, edge_item, DIS,
                                                 ROWPTR, EPOS, CSRE);
    k_mark<<<(2 * BATCH + 255) / 256, 256, 0, stream>>>(user_idx, pos_item_id,
                                                        ROWPTR, CSRE, FLAGS);

    k_prop<false><<<(NN + 3) / 4, 256, 0, stream>>>(XB0, ROWPTR, CSRE, XB1, nullptr);
    k_prop<true><<<(NN + 3) / 4, 256, 0, stream>>>(XB1, ROWPTR, CSRE, XB0, FLAGS);

    k_tail<<<BATCH / 4, 256, 0, stream>>>(XB0, ROWPTR, CSRE, user_idx,
                                          pos_item_id, (float*)d_out);
}

// Round 3
// 351.101 us; speedup vs baseline: 1.2826x; 1.2826x over previous
//
#include <hip/hip_runtime.h>
#include <math.h>

#define NU 200000
#define NI 100000
#define NN 300000
#define DD 64
#define EDGES 1000000
#define E2 2000000
#define BATCH 4096
#define SCAN_CHUNK 1024
#define NBLK1 ((NN + SCAN_CHUNK - 1) / SCAN_CHUNK)   // 293
#define FIX_SCALE 131072.0f                           // 2^17
#define FIX_INV   7.62939453125e-06f                  // 2^-17

#define MLP_BLOCKS4 ((E2 + 1023) / 1024) // 1954 (4 edges/thread, 1024 edges/block)
#define FUSE_BLOCKS4 (NI / 16)           // 6250 (16 items/block, 4 per wave)
#define COPY_BLOCKS (NU * DD / 4 / 256)  // 12500
#define PREP_PERIODS 2084
#define PREP_GRID (PREP_PERIODS * 10)    // 20840, period-10: {A,B,B,B,C,C,C,C,C,C}

__device__ __forceinline__ unsigned short f2bf(float f) {  // RNE
    unsigned u = __float_as_uint(f);
    return (unsigned short)((u + 0x7fffu + ((u >> 16) & 1u)) >> 16);
}
__device__ __forceinline__ float bflo(unsigned v) { return __uint_as_float(v << 16); }
__device__ __forceinline__ float bfhi(unsigned v) { return __uint_as_float(v & 0xffff0000u); }

// fused prep, period-10 stripe {A,B,B,B,C,C,C,C,C,C}.
// role A: edge MLP -> w, packed u32 deg/count atomic, epos (4 edges/thread,
//         weights staged in LDS -- LDS broadcast reads amortized over 4 edges)
// role B: item fuse + adapter + l2norm -> bf16 x rows [NU, NN) (4 items/wave)
// role C: f32->bf16 copy of user rows [0, NU)
__global__ __launch_bounds__(256) void k_prep(
    const float* __restrict__ ef, const float* __restrict__ W1,
    const float* __restrict__ b1, const float* __restrict__ W2,
    const float* __restrict__ b2, const int* __restrict__ eu,
    const int* __restrict__ ei, float* __restrict__ w,
    unsigned* __restrict__ degc, int* __restrict__ epos,
    const float* __restrict__ item_audio, const float* __restrict__ artist_emb,
    const float* __restrict__ album_emb, const int* __restrict__ artist_ids,
    const int* __restrict__ album_ids, const float* __restrict__ aW,
    const float* __restrict__ ab, const float* __restrict__ user_emb,
    unsigned short* __restrict__ x) {
    __shared__ float4 sW4[64][16];          // role B: adapter, XOR-swizzled (16 KiB)
    __shared__ float4 sv4[16][16];          // role B: fused item vectors (4 KiB)
    __shared__ float4 sW1v[64];             // role A: W1 as 64 float4 (1 KiB)
    __shared__ float sb1[32], sW2s[32], sb2v;
    int bid = blockIdx.x;
    int tid = threadIdx.x;
    int r = bid % 10, base = bid / 10;
    if (r == 0) {                               // ---- role A: edge MLP + deg
        if (base >= MLP_BLOCKS4) return;
        if (tid < 64) sW1v[tid] = ((const float4*)W1)[tid];
        else if (tid < 96) sb1[tid - 64] = b1[tid - 64];
        else if (tid < 128) sW2s[tid - 96] = W2[tid - 96];
        else if (tid == 128) sb2v = b2[0];
        __syncthreads();
        int ebase = base * 1024 + tid;          // edges ebase + {0,256,512,768}
        float4 f0[4], f1[4];
#pragma unroll
        for (int t = 0; t < 4; ++t) {
            int e = ebase + t * 256;
            int ec = e < E2 ? e : 0;            // clamp loads, guard stores
            f0[t] = ((const float4*)ef)[2 * ec];
            f1[t] = ((const float4*)ef)[2 * ec + 1];
        }
        float z0 = sb2v, z1 = sb2v, z2 = sb2v, z3 = sb2v;
#pragma unroll 8
        for (int i = 0; i < 32; ++i) {
            float4 wa = sW1v[2 * i], wb = sW1v[2 * i + 1];
            float bi = sb1[i], wo = sW2s[i];
            float a0 = bi + f0[0].x * wa.x + f0[0].y * wa.y + f0[0].z * wa.z +
                       f0[0].w * wa.w + f1[0].x * wb.x + f1[0].y * wb.y +
                       f1[0].z * wb.z + f1[0].w * wb.w;
            float a1 = bi + f0[1].x * wa.x + f0[1].y * wa.y + f0[1].z * wa.z +
                       f0[1].w * wa.w + f1[1].x * wb.x + f1[1].y * wb.y +
                       f1[1].z * wb.z + f1[1].w * wb.w;
            float a2 = bi + f0[2].x * wa.x + f0[2].y * wa.y + f0[2].z * wa.z +
                       f0[2].w * wa.w + f1[2].x * wb.x + f1[2].y * wb.y +
                       f1[2].z * wb.z + f1[2].w * wb.w;
            float a3 = bi + f0[3].x * wa.x + f0[3].y * wa.y + f0[3].z * wa.z +
                       f0[3].w * wa.w + f1[3].x * wb.x + f1[3].y * wb.y +
                       f1[3].z * wb.z + f1[3].w * wb.w;
            z0 += wo * fmaxf(a0, 0.0f);
            z1 += wo * fmaxf(a1, 0.0f);
            z2 += wo * fmaxf(a2, 0.0f);
            z3 += wo * fmaxf(a3, 0.0f);
        }
        float zz[4] = {z0, z1, z2, z3};
#pragma unroll
        for (int t = 0; t < 4; ++t) {
            int e = ebase + t * 256;
            if (e < E2) {
                float we = 1.0f / (1.0f + __expf(-zz[t]));
                w[e] = we;
                int c = (e < EDGES) ? (NU + ei[e]) : eu[e - EDGES];
                unsigned old = atomicAdd(
                    &degc[c], (1u << 24) | (unsigned)(we * FIX_SCALE + 0.5f));
                epos[e] = (int)(old >> 24);
            }
        }
        return;
    }
    if (r <= 3) {                               // ---- role B: item fuse
        int j = base * 3 + (r - 1);
        if (j >= FUSE_BLOCKS4) return;
#pragma unroll
        for (int s = 0; s < 4; ++s) {
            int i4 = tid + s * 256;
            int row = i4 >> 4, c4 = i4 & 15;
            sW4[row][(c4 & 8) | ((c4 ^ row) & 7)] = ((const float4*)aW)[i4];
        }
        __syncthreads();
        int wave = tid >> 6, lane = tid & 63;
        int it0 = j * 16 + wave * 4;            // items it0..it0+3
        float* svf = (float*)sv4;
#pragma unroll
        for (int t = 0; t < 4; ++t) {
            int it = it0 + t;
            int ar = artist_ids[it], al = album_ids[it];
            float v = item_audio[it * DD + lane] + artist_emb[ar * DD + lane] +
                      album_emb[al * DD + lane];
            svf[(wave * 4 + t) * DD + lane] = v;   // same-wave use: no barrier
        }
        float bias = ab[lane];
        float t0 = bias, t1 = bias, t2 = bias, t3 = bias;
#pragma unroll
        for (int k4 = 0; k4 < 16; ++k4) {
            float4 wv = sW4[lane][(k4 & 8) | ((k4 ^ lane) & 7)];
            float4 va = sv4[wave * 4 + 0][k4];  // uniform broadcasts
            float4 vb = sv4[wave * 4 + 1][k4];
            float4 vc = sv4[wave * 4 + 2][k4];
            float4 vd = sv4[wave * 4 + 3][k4];
            t0 += wv.x * va.x + wv.y * va.y + wv.z * va.z + wv.w * va.w;
            t1 += wv.x * vb.x + wv.y * vb.y + wv.z * vb.z + wv.w * vb.w;
            t2 += wv.x * vc.x + wv.y * vc.y + wv.z * vc.z + wv.w * vc.w;
            t3 += wv.x * vd.x + wv.y * vd.y + wv.z * vd.z + wv.w * vd.w;
        }
        float s0 = t0 * t0, s1 = t1 * t1, s2 = t2 * t2, s3 = t3 * t3;
        for (int m = 32; m >= 1; m >>= 1) {
            s0 += __shfl_xor(s0, m, 64);
            s1 += __shfl_xor(s1, m, 64);
            s2 += __shfl_xor(s2, m, 64);
            s3 += __shfl_xor(s3, m, 64);
        }
        x[(NU + it0 + 0) * DD + lane] = f2bf(t0 / fmaxf(sqrtf(s0), 1e-12f));
        x[(NU + it0 + 1) * DD + lane] = f2bf(t1 / fmaxf(sqrtf(s1), 1e-12f));
        x[(NU + it0 + 2) * DD + lane] = f2bf(t2 / fmaxf(sqrtf(s2), 1e-12f));
        x[(NU + it0 + 3) * DD + lane] = f2bf(t3 / fmaxf(sqrtf(s3), 1e-12f));
        return;
    }
    int cb = base * 6 + (r - 4);                // ---- role C: copy users
    if (cb >= COPY_BLOCKS) return;
    int i = cb * 256 + tid;
    float4 v = ((const float4*)user_emb)[i];
    ushort4 o;
    o.x = f2bf(v.x); o.y = f2bf(v.y); o.z = f2bf(v.z); o.w = f2bf(v.w);
    ((ushort4*)x)[i] = o;
}

// ---- exclusive prefix sum over PADDED counts (ceil(cnt/8)*8) -> rowptr ----
__global__ __launch_bounds__(1024) void k_scan_local(
    const unsigned* __restrict__ degc, int* __restrict__ rowptr,
    int* __restrict__ bsum) {
    __shared__ int sh[SCAN_CHUNK];
    int tid = threadIdx.x;
    int i = blockIdx.x * SCAN_CHUNK + tid;
    int cnt = (i < NN) ? (int)(degc[i] >> 24) : 0;
    int v = (cnt + 7) & ~7;
    sh[tid] = v;
    __syncthreads();
    for (int off = 1; off < SCAN_CHUNK; off <<= 1) {
        int t = (tid >= off) ? sh[tid - off] : 0;
        __syncthreads();
        sh[tid] += t;
        __syncthreads();
    }
    if (i < NN) rowptr[i] = sh[tid] - v;  // exclusive
    if (tid == SCAN_CHUNK - 1) bsum[blockIdx.x] = sh[tid];
}

__global__ __launch_bounds__(512) void k_scan_bsum(int* __restrict__ bsum) {
    __shared__ int sh[512];
    int tid = threadIdx.x;
    int v = (tid < NBLK1) ? bsum[tid] : 0;
    sh[tid] = v;
    __syncthreads();
    for (int off = 1; off < 512; off <<= 1) {
        int t = (tid >= off) ? sh[tid - off] : 0;
        __syncthreads();
        sh[tid] += t;
        __syncthreads();
    }
    if (tid < NBLK1) bsum[tid] = sh[tid] - v;  // exclusive
}

// rowptr += block offsets; dis = rsqrt(degree); zero the pad slots of csre
__global__ void k_scan_add_dis(int* __restrict__ rowptr, const int* __restrict__ bsum,
                               const unsigned* __restrict__ degc,
                               float* __restrict__ dis, int2* __restrict__ csre) {
    int i = blockIdx.x * blockDim.x + threadIdx.x;
    if (i >= NN) return;
    int rp = rowptr[i] + bsum[i >> 10];
    rowptr[i] = rp;
    unsigned dc = degc[i];
    int cnt = (int)(dc >> 24);
    int pcnt = (cnt + 7) & ~7;
    float d = (float)(dc & 0xFFFFFFu) * FIX_INV;
    dis[i] = d > 0.0f ? rsqrtf(d) : 0.0f;
    for (int k = cnt; k < pcnt; ++k) csre[rp + k] = make_int2(0, 0);  // pad: row0,w=0
    if (i == NN - 1) rowptr[NN] = rp + pcnt;
}

// fill CSR: atomic-free; slot = {source row BYTE offset, fused gcn weight}
__global__ void k_fill(const float* __restrict__ w, const int* __restrict__ eu,
                       const int* __restrict__ ei, const float* __restrict__ dis,
                       const int* __restrict__ rowptr, const int* __restrict__ epos,
                       int2* __restrict__ csre) {
    int e = blockIdx.x * blockDim.x + threadIdx.x;
    if (e >= E2) return;
    int r, c;
    if (e < EDGES) { r = eu[e]; c = NU + ei[e]; }
    else           { r = NU + ei[e - EDGES]; c = eu[e - EDGES]; }
    int pos = rowptr[c] + epos[e];
    csre[pos] = make_int2(r * (DD * 2), __float_as_int(dis[r] * w[e] * dis[c]));
}

// mark nodes whose z2 is consumed by the tail (sources of batch-row buckets)
__global__ void k_mark(const int* __restrict__ uidx, const int* __restrict__ pidx,
                       const int* __restrict__ rowptr, const int2* __restrict__ csre,
                       unsigned char* __restrict__ flags) {
    int t = blockIdx.x * blockDim.x + threadIdx.x;
    if (t >= 2 * BATCH) return;
    int row = (t < BATCH) ? uidx[t] : NU + pidx[t - BATCH];
    int beg = rowptr[row], end = rowptr[row + 1];
    for (int e = beg; e < end; ++e) flags[((unsigned)csre[e].x) >> 7] = 1;
}

// quarter-wave pull: 16 lanes cover a row (4 dims each via 8B gather),
// quarter q handles edges e+2q, e+2q+1; csre read as int4 (2 edges/load).
__device__ __forceinline__ void pull4(const char* __restrict__ xb,
                                      const int2* __restrict__ csre,
                                      int beg, int end, int q2, int t8,
                                      float& a0, float& a1, float& a2, float& a3) {
    a0 = a1 = a2 = a3 = 0.0f;
    for (int e = beg; e < end; e += 8) {
        int4 s = *(const int4*)(csre + (e + q2));   // {offA,wA,offB,wB}
        uint2 va = *(const uint2*)(xb + (unsigned)s.x + t8);
        uint2 vb = *(const uint2*)(xb + (unsigned)s.z + t8);
        float wa = __int_as_float(s.y), wb = __int_as_float(s.w);
        a0 = fmaf(bflo(va.x), wa, a0);
        a1 = fmaf(bfhi(va.x), wa, a1);
        a2 = fmaf(bflo(va.y), wa, a2);
        a3 = fmaf(bfhi(va.y), wa, a3);
        a0 = fmaf(bflo(vb.x), wb, a0);
        a1 = fmaf(bfhi(vb.x), wb, a1);
        a2 = fmaf(bflo(vb.y), wb, a2);
        a3 = fmaf(bfhi(vb.y), wb, a3);
    }
    a0 += __shfl_xor(a0, 16, 64); a1 += __shfl_xor(a1, 16, 64);
    a2 += __shfl_xor(a2, 16, 64); a3 += __shfl_xor(a3, 16, 64);
    a0 += __shfl_xor(a0, 32, 64); a1 += __shfl_xor(a1, 32, 64);
    a2 += __shfl_xor(a2, 32, 64); a3 += __shfl_xor(a3, 32, 64);
}

// propagation layer (bf16 -> bf16), one wave per node; FLAGS: skip unmarked
template <bool FLAGS>
__global__ __launch_bounds__(256) void k_prop(
    const unsigned short* __restrict__ x, const int* __restrict__ rowptr,
    const int2* __restrict__ csre, unsigned short* __restrict__ xn,
    const unsigned char* __restrict__ flags) {
    int tid = threadIdx.x;
    int node = blockIdx.x * 4 + (tid >> 6);
    if (node >= NN) return;
    if (FLAGS && !flags[node]) return;
    int lane = tid & 63;
    int q2 = (lane >> 4) << 1;
    int t8 = (lane & 15) * 8;
    float a0, a1, a2, a3;
    pull4((const char*)x, csre, rowptr[node], rowptr[node + 1], q2, t8,
          a0, a1, a2, a3);
    if ((lane >> 4) == 0) {
        unsigned lo = ((unsigned)f2bf(a1) << 16) | (unsigned)f2bf(a0);
        unsigned hi = ((unsigned)f2bf(a3) << 16) | (unsigned)f2bf(a2);
        *(uint2*)((char*)xn + (size_t)node * 128 + t8) = make_uint2(lo, hi);
    }
}

// layer-3 + l2norm + cosine loss, only for the 2*BATCH consumed rows
__global__ __launch_bounds__(256) void k_tail(
    const unsigned short* __restrict__ x, const int* __restrict__ rowptr,
    const int2* __restrict__ csre, const int* __restrict__ uidx,
    const int* __restrict__ pidx, float* __restrict__ out) {
    int tid = threadIdx.x;
    int b = blockIdx.x * 4 + (tid >> 6);
    if (b >= BATCH) return;
    int lane = tid & 63;
    int q2 = (lane >> 4) << 1;
    int t8 = (lane & 15) * 8;
    const char* xb = (const char*)x;
    int un = uidx[b], pn = NU + pidx[b];
    float u0, u1, u2, u3, p0, p1, p2, p3, ss, s;
    pull4(xb, csre, rowptr[un], rowptr[un + 1], q2, t8, u0, u1, u2, u3);
    ss = u0 * u0 + u1 * u1 + u2 * u2 + u3 * u3;
    for (int m = 8; m >= 1; m >>= 1) ss += __shfl_xor(ss, m, 64);
    s = 1.0f / fmaxf(sqrtf(ss), 1e-12f);
    u0 *= s; u1 *= s; u2 *= s; u3 *= s;
    pull4(xb, csre, rowptr[pn], rowptr[pn + 1], q2, t8, p0, p1, p2, p3);
    ss = p0 * p0 + p1 * p1 + p2 * p2 + p3 * p3;
    for (int m = 8; m >= 1; m >>= 1) ss += __shfl_xor(ss, m, 64);
    s = 1.0f / fmaxf(sqrtf(ss), 1e-12f);
    p0 *= s; p1 *= s; p2 *= s; p3 *= s;
    if ((lane >> 4) == 0)
        ((float4*)out)[b * 16 + (t8 >> 3)] = make_float4(u0, u1, u2, u3);
    float dot = u0 * p0 + u1 * p1 + u2 * p2 + u3 * p3;
    float uu = u0 * u0 + u1 * u1 + u2 * u2 + u3 * u3;
    float pp = p0 * p0 + p1 * p1 + p2 * p2 + p3 * p3;
    for (int m = 8; m >= 1; m >>= 1) {
        dot += __shfl_xor(dot, m, 64);
        uu  += __shfl_xor(uu, m, 64);
        pp  += __shfl_xor(pp, m, 64);
    }
    if (lane == 0) {
        float cs = dot / (fmaxf(sqrtf(uu), 1e-8f) * fmaxf(sqrtf(pp), 1e-8f));
        atomicAdd(out + BATCH * DD, (1.0f - cs) * (1.0f / BATCH));
    }
}

extern "C" void kernel_launch(void* const* d_in, const int* in_sizes, int n_in,
                              void* d_out, int out_size, void* d_ws, size_t ws_size,
                              hipStream_t stream) {
    const float* user_emb      = (const float*)d_in[0];
    const float* artist_emb    = (const float*)d_in[1];
    const float* album_emb     = (const float*)d_in[2];
    const float* item_audio    = (const float*)d_in[3];
    const float* adapter_W     = (const float*)d_in[4];
    const float* adapter_b     = (const float*)d_in[5];
    const float* mlp_W1        = (const float*)d_in[6];
    const float* mlp_b1        = (const float*)d_in[7];
    const float* mlp_W2        = (const float*)d_in[8];
    const float* mlp_b2        = (const float*)d_in[9];
    const float* edge_features = (const float*)d_in[10];
    const int*   edge_user     = (const int*)d_in[11];
    const int*   edge_item     = (const int*)d_in[12];
    const int*   artist_ids    = (const int*)d_in[13];
    const int*   album_ids     = (const int*)d_in[14];
    const int*   user_idx      = (const int*)d_in[15];
    const int*   pos_item_id   = (const int*)d_in[16];

    char* p = (char*)d_ws;
    unsigned short* XB0 = (unsigned short*)p; p += (size_t)NN * DD * 2;
    unsigned short* XB1 = (unsigned short*)p; p += (size_t)NN * DD * 2;
    float* W       = (float*)p; p += (size_t)E2 * 4;
    int2*  CSRE    = (int2*)p;  p += (size_t)4200000 * 8;   // padded CSR
    int*   EPOS    = (int*)p;   p += (size_t)E2 * 4;
    unsigned* DEGC = (unsigned*)p; p += (size_t)NN * 8;     // u32 used, u64 reserved
    float* DIS     = (float*)p; p += (size_t)NN * 4;
    int*   ROWPTR  = (int*)p;   p += (size_t)(NN + 1) * 4;
    int*   BSUM    = (int*)p;   p += (size_t)((NBLK1 + 3) & ~3) * 4;
    unsigned char* FLAGS = (unsigned char*)p; p += (size_t)NN;

    hipMemsetAsync(DEGC, 0, NN * sizeof(unsigned), stream);
    hipMemsetAsync(FLAGS, 0, NN, stream);
    hipMemsetAsync((float*)d_out + BATCH * DD, 0, sizeof(float), stream);

    k_prep<<<PREP_GRID, 256, 0, stream>>>(
        edge_features, mlp_W1, mlp_b1, mlp_W2, mlp_b2, edge_user, edge_item,
        W, DEGC, EPOS, item_audio, artist_emb, album_emb, artist_ids, album_ids,
        adapter_W, adapter_b, user_emb, XB0);

    k_scan_local<<<NBLK1, SCAN_CHUNK, 0, stream>>>(DEGC, ROWPTR, BSUM);
    k_scan_bsum<<<1, 512, 0, stream>>>(BSUM);
    k_scan_add_dis<<<(NN + 255) / 256, 256, 0, stream>>>(ROWPTR, BSUM, DEGC, DIS,
                                                         CSRE);
    k_fill<<<(E2 + 255) / 256, 256, 0, stream>>>(W, edge_user, edge_item, DIS,
                                                 ROWPTR, EPOS, CSRE);
    k_mark<<<(2 * BATCH + 255) / 256, 256, 0, stream>>>(user_idx, pos_item_id,
                                                        ROWPTR, CSRE, FLAGS);

    k_prop<false><<<(NN + 3) / 4, 256, 0, stream>>>(XB0, ROWPTR, CSRE, XB1, nullptr);
    k_prop<true><<<(NN + 3) / 4, 256, 0, stream>>>(XB1, ROWPTR, CSRE, XB0, FLAGS);

    k_tail<<<BATCH / 4, 256, 0, stream>>>(XB0, ROWPTR, CSRE, user_idx,
                                          pos_item_id, (float*)d_out);
}

// Round 4
// 344.191 us; speedup vs baseline: 1.3084x; 1.0201x over previous
//
#include <hip/hip_runtime.h>
#include <math.h>

#define NU 200000
#define NI 100000
#define NN 300000
#define DD 64
#define EDGES 1000000
#define E2 2000000
#define BATCH 4096
#define SCAN_CHUNK 1024
#define NBLK1 ((NN + SCAN_CHUNK - 1) / SCAN_CHUNK)   // 293
#define FIX_SCALE 131072.0f                           // 2^17
#define FIX_INV   7.62939453125e-06f                  // 2^-17

#define MLP_BLOCKS2 ((E2 + 511) / 512)   // 3907 (2 edges/thread, 512 edges/block)
#define FUSE_BLOCKS4 (NI / 16)           // 6250 (16 items/block, 4 per wave)
#define COPY_BLOCKS (NU * DD / 4 / 256)  // 12500
#define PREP_PERIODS 2084
#define PREP_GRID (PREP_PERIODS * 11)    // 22924, period-11: {A,A,B,B,B,C,C,C,C,C,C}

__device__ __forceinline__ unsigned short f2bf(float f) {  // RNE
    unsigned u = __float_as_uint(f);
    return (unsigned short)((u + 0x7fffu + ((u >> 16) & 1u)) >> 16);
}
__device__ __forceinline__ float bflo(unsigned v) { return __uint_as_float(v << 16); }
__device__ __forceinline__ float bfhi(unsigned v) { return __uint_as_float(v & 0xffff0000u); }

// fused prep, period-11 stripe {A,A,B,B,B,C,C,C,C,C,C}.
// role A: edge MLP -> w, packed u32 deg/count atomic, epos (2 edges/thread,
//         LDS-staged weights; column-index gather hoisted above MLP loop)
// role B: item fuse + adapter + l2norm -> bf16 x rows [NU, NN) (4 items/wave)
// role C: f32->bf16 copy of user rows [0, NU)
__global__ __launch_bounds__(256) void k_prep(
    const float* __restrict__ ef, const float* __restrict__ W1,
    const float* __restrict__ b1, const float* __restrict__ W2,
    const float* __restrict__ b2, const int* __restrict__ eu,
    const int* __restrict__ ei, float* __restrict__ w,
    unsigned* __restrict__ degc, int* __restrict__ epos,
    const float* __restrict__ item_audio, const float* __restrict__ artist_emb,
    const float* __restrict__ album_emb, const int* __restrict__ artist_ids,
    const int* __restrict__ album_ids, const float* __restrict__ aW,
    const float* __restrict__ ab, const float* __restrict__ user_emb,
    unsigned short* __restrict__ x) {
    __shared__ float4 sW4[64][16];          // role B: adapter, XOR-swizzled (16 KiB)
    __shared__ float4 sv4[16][16];          // role B: fused item vectors (4 KiB)
    __shared__ float4 sW1v[64];             // role A: W1 as 64 float4 (1 KiB)
    __shared__ float sb1[32], sW2s[32], sb2v;
    int bid = blockIdx.x;
    int tid = threadIdx.x;
    int r = bid % 11, base = bid / 11;
    if (r < 2) {                                // ---- role A: edge MLP + deg
        int ablk = base * 2 + r;
        if (ablk >= MLP_BLOCKS2) return;
        if (tid < 64) sW1v[tid] = ((const float4*)W1)[tid];
        else if (tid < 96) sb1[tid - 64] = b1[tid - 64];
        else if (tid < 128) sW2s[tid - 96] = W2[tid - 96];
        else if (tid == 128) sb2v = b2[0];
        __syncthreads();
        int e0 = ablk * 512 + tid;
        int e1 = e0 + 256;
        int e0c = e0 < E2 ? e0 : 0;             // clamp loads, guard stores
        int e1c = e1 < E2 ? e1 : 0;
        // hoist column-index gathers: latency hides under the MLP loop
        int c0 = (e0c < EDGES) ? (NU + ei[e0c]) : eu[e0c - EDGES];
        int c1 = (e1c < EDGES) ? (NU + ei[e1c]) : eu[e1c - EDGES];
        float4 fa0 = ((const float4*)ef)[2 * e0c];
        float4 fa1 = ((const float4*)ef)[2 * e0c + 1];
        float4 fb0 = ((const float4*)ef)[2 * e1c];
        float4 fb1 = ((const float4*)ef)[2 * e1c + 1];
        float z0 = sb2v, z1 = sb2v;
#pragma unroll 8
        for (int i = 0; i < 32; ++i) {
            float4 wa = sW1v[2 * i], wb = sW1v[2 * i + 1];
            float bi = sb1[i], wo = sW2s[i];
            float a0 = bi + fa0.x * wa.x + fa0.y * wa.y + fa0.z * wa.z +
                       fa0.w * wa.w + fa1.x * wb.x + fa1.y * wb.y +
                       fa1.z * wb.z + fa1.w * wb.w;
            float a1 = bi + fb0.x * wa.x + fb0.y * wa.y + fb0.z * wa.z +
                       fb0.w * wa.w + fb1.x * wb.x + fb1.y * wb.y +
                       fb1.z * wb.z + fb1.w * wb.w;
            z0 += wo * fmaxf(a0, 0.0f);
            z1 += wo * fmaxf(a1, 0.0f);
        }
        if (e0 < E2) {
            float we = 1.0f / (1.0f + __expf(-z0));
            w[e0] = we;
            unsigned old = atomicAdd(
                &degc[c0], (1u << 24) | (unsigned)(we * FIX_SCALE + 0.5f));
            epos[e0] = (int)(old >> 24);
        }
        if (e1 < E2) {
            float we = 1.0f / (1.0f + __expf(-z1));
            w[e1] = we;
            unsigned old = atomicAdd(
                &degc[c1], (1u << 24) | (unsigned)(we * FIX_SCALE + 0.5f));
            epos[e1] = (int)(old >> 24);
        }
        return;
    }
    if (r <= 4) {                               // ---- role B: item fuse
        int j = base * 3 + (r - 2);
        if (j >= FUSE_BLOCKS4) return;
#pragma unroll
        for (int s = 0; s < 4; ++s) {
            int i4 = tid + s * 256;
            int row = i4 >> 4, c4 = i4 & 15;
            sW4[row][(c4 & 8) | ((c4 ^ row) & 7)] = ((const float4*)aW)[i4];
        }
        __syncthreads();
        int wave = tid >> 6, lane = tid & 63;
        int it0 = j * 16 + wave * 4;            // items it0..it0+3
        float* svf = (float*)sv4;
#pragma unroll
        for (int t = 0; t < 4; ++t) {
            int it = it0 + t;
            int ar = artist_ids[it], al = album_ids[it];
            float v = item_audio[it * DD + lane] + artist_emb[ar * DD + lane] +
                      album_emb[al * DD + lane];
            svf[(wave * 4 + t) * DD + lane] = v;   // same-wave use: no barrier
        }
        float bias = ab[lane];
        float t0 = bias, t1 = bias, t2 = bias, t3 = bias;
#pragma unroll
        for (int k4 = 0; k4 < 16; ++k4) {
            float4 wv = sW4[lane][(k4 & 8) | ((k4 ^ lane) & 7)];
            float4 va = sv4[wave * 4 + 0][k4];  // uniform broadcasts
            float4 vb = sv4[wave * 4 + 1][k4];
            float4 vc = sv4[wave * 4 + 2][k4];
            float4 vd = sv4[wave * 4 + 3][k4];
            t0 += wv.x * va.x + wv.y * va.y + wv.z * va.z + wv.w * va.w;
            t1 += wv.x * vb.x + wv.y * vb.y + wv.z * vb.z + wv.w * vb.w;
            t2 += wv.x * vc.x + wv.y * vc.y + wv.z * vc.z + wv.w * vc.w;
            t3 += wv.x * vd.x + wv.y * vd.y + wv.z * vd.z + wv.w * vd.w;
        }
        float s0 = t0 * t0, s1 = t1 * t1, s2 = t2 * t2, s3 = t3 * t3;
        for (int m = 32; m >= 1; m >>= 1) {
            s0 += __shfl_xor(s0, m, 64);
            s1 += __shfl_xor(s1, m, 64);
            s2 += __shfl_xor(s2, m, 64);
            s3 += __shfl_xor(s3, m, 64);
        }
        x[(NU + it0 + 0) * DD + lane] = f2bf(t0 / fmaxf(sqrtf(s0), 1e-12f));
        x[(NU + it0 + 1) * DD + lane] = f2bf(t1 / fmaxf(sqrtf(s1), 1e-12f));
        x[(NU + it0 + 2) * DD + lane] = f2bf(t2 / fmaxf(sqrtf(s2), 1e-12f));
        x[(NU + it0 + 3) * DD + lane] = f2bf(t3 / fmaxf(sqrtf(s3), 1e-12f));
        return;
    }
    int cb = base * 6 + (r - 5);                // ---- role C: copy users
    if (cb >= COPY_BLOCKS) return;
    int i = cb * 256 + tid;
    float4 v = ((const float4*)user_emb)[i];
    ushort4 o;
    o.x = f2bf(v.x); o.y = f2bf(v.y); o.z = f2bf(v.z); o.w = f2bf(v.w);
    ((ushort4*)x)[i] = o;
}

// ---- exclusive prefix sum over PADDED counts (ceil(cnt/8)*8) -> rowptr ----
__global__ __launch_bounds__(1024) void k_scan_local(
    const unsigned* __restrict__ degc, int* __restrict__ rowptr,
    int* __restrict__ bsum) {
    __shared__ int sh[SCAN_CHUNK];
    int tid = threadIdx.x;
    int i = blockIdx.x * SCAN_CHUNK + tid;
    int cnt = (i < NN) ? (int)(degc[i] >> 24) : 0;
    int v = (cnt + 7) & ~7;
    sh[tid] = v;
    __syncthreads();
    for (int off = 1; off < SCAN_CHUNK; off <<= 1) {
        int t = (tid >= off) ? sh[tid - off] : 0;
        __syncthreads();
        sh[tid] += t;
        __syncthreads();
    }
    if (i < NN) rowptr[i] = sh[tid] - v;  // exclusive
    if (tid == SCAN_CHUNK - 1) bsum[blockIdx.x] = sh[tid];
}

__global__ __launch_bounds__(512) void k_scan_bsum(int* __restrict__ bsum) {
    __shared__ int sh[512];
    int tid = threadIdx.x;
    int v = (tid < NBLK1) ? bsum[tid] : 0;
    sh[tid] = v;
    __syncthreads();
    for (int off = 1; off < 512; off <<= 1) {
        int t = (tid >= off) ? sh[tid - off] : 0;
        __syncthreads();
        sh[tid] += t;
        __syncthreads();
    }
    if (tid < NBLK1) bsum[tid] = sh[tid] - v;  // exclusive
}

// rowptr += block offsets; dis = rsqrt(degree); zero the pad slots of csre
__global__ void k_scan_add_dis(int* __restrict__ rowptr, const int* __restrict__ bsum,
                               const unsigned* __restrict__ degc,
                               float* __restrict__ dis, int2* __restrict__ csre) {
    int i = blockIdx.x * blockDim.x + threadIdx.x;
    if (i >= NN) return;
    int rp = rowptr[i] + bsum[i >> 10];
    rowptr[i] = rp;
    unsigned dc = degc[i];
    int cnt = (int)(dc >> 24);
    int pcnt = (cnt + 7) & ~7;
    float d = (float)(dc & 0xFFFFFFu) * FIX_INV;
    dis[i] = d > 0.0f ? rsqrtf(d) : 0.0f;
    for (int k = cnt; k < pcnt; ++k) csre[rp + k] = make_int2(0, 0);  // pad: row0,w=0
    if (i == NN - 1) rowptr[NN] = rp + pcnt;
}

// fill CSR: atomic-free; slot = {source row BYTE offset, fused gcn weight}
__global__ void k_fill(const float* __restrict__ w, const int* __restrict__ eu,
                       const int* __restrict__ ei, const float* __restrict__ dis,
                       const int* __restrict__ rowptr, const int* __restrict__ epos,
                       int2* __restrict__ csre) {
    int e = blockIdx.x * blockDim.x + threadIdx.x;
    if (e >= E2) return;
    int r, c;
    if (e < EDGES) { r = eu[e]; c = NU + ei[e]; }
    else           { r = NU + ei[e - EDGES]; c = eu[e - EDGES]; }
    int pos = rowptr[c] + epos[e];
    csre[pos] = make_int2(r * (DD * 2), __float_as_int(dis[r] * w[e] * dis[c]));
}

// mark nodes whose z2 is consumed by the tail (sources of batch-row buckets)
__global__ void k_mark(const int* __restrict__ uidx, const int* __restrict__ pidx,
                       const int* __restrict__ rowptr, const int2* __restrict__ csre,
                       unsigned char* __restrict__ flags) {
    int t = blockIdx.x * blockDim.x + threadIdx.x;
    if (t >= 2 * BATCH) return;
    int row = (t < BATCH) ? uidx[t] : NU + pidx[t - BATCH];
    int beg = rowptr[row], end = rowptr[row + 1];
    for (int e = beg; e < end; ++e) flags[((unsigned)csre[e].x) >> 7] = 1;
}

// quarter-wave pull: 16 lanes cover a row (4 dims each via 8B gather),
// quarter q handles edges e+2q, e+2q+1; csre read as int4 (2 edges/load).
__device__ __forceinline__ void pull4(const char* __restrict__ xb,
                                      const int2* __restrict__ csre,
                                      int beg, int end, int q2, int t8,
                                      float& a0, float& a1, float& a2, float& a3) {
    a0 = a1 = a2 = a3 = 0.0f;
    for (int e = beg; e < end; e += 8) {
        int4 s = *(const int4*)(csre + (e + q2));   // {offA,wA,offB,wB}
        uint2 va = *(const uint2*)(xb + (unsigned)s.x + t8);
        uint2 vb = *(const uint2*)(xb + (unsigned)s.z + t8);
        float wa = __int_as_float(s.y), wb = __int_as_float(s.w);
        a0 = fmaf(bflo(va.x), wa, a0);
        a1 = fmaf(bfhi(va.x), wa, a1);
        a2 = fmaf(bflo(va.y), wa, a2);
        a3 = fmaf(bfhi(va.y), wa, a3);
        a0 = fmaf(bflo(vb.x), wb, a0);
        a1 = fmaf(bfhi(vb.x), wb, a1);
        a2 = fmaf(bflo(vb.y), wb, a2);
        a3 = fmaf(bfhi(vb.y), wb, a3);
    }
    a0 += __shfl_xor(a0, 16, 64); a1 += __shfl_xor(a1, 16, 64);
    a2 += __shfl_xor(a2, 16, 64); a3 += __shfl_xor(a3, 16, 64);
    a0 += __shfl_xor(a0, 32, 64); a1 += __shfl_xor(a1, 32, 64);
    a2 += __shfl_xor(a2, 32, 64); a3 += __shfl_xor(a3, 32, 64);
}

// propagation layer (bf16 -> bf16), one wave per node; FLAGS: skip unmarked
template <bool FLAGS>
__global__ __launch_bounds__(256) void k_prop(
    const unsigned short* __restrict__ x, const int* __restrict__ rowptr,
    const int2* __restrict__ csre, unsigned short* __restrict__ xn,
    const unsigned char* __restrict__ flags) {
    int tid = threadIdx.x;
    int node = blockIdx.x * 4 + (tid >> 6);
    if (node >= NN) return;
    if (FLAGS && !flags[node]) return;
    int lane = tid & 63;
    int q2 = (lane >> 4) << 1;
    int t8 = (lane & 15) * 8;
    float a0, a1, a2, a3;
    pull4((const char*)x, csre, rowptr[node], rowptr[node + 1], q2, t8,
          a0, a1, a2, a3);
    if ((lane >> 4) == 0) {
        unsigned lo = ((unsigned)f2bf(a1) << 16) | (unsigned)f2bf(a0);
        unsigned hi = ((unsigned)f2bf(a3) << 16) | (unsigned)f2bf(a2);
        *(uint2*)((char*)xn + (size_t)node * 128 + t8) = make_uint2(lo, hi);
    }
}

// layer-3 + l2norm + cosine loss, only for the 2*BATCH consumed rows
__global__ __launch_bounds__(256) void k_tail(
    const unsigned short* __restrict__ x, const int* __restrict__ rowptr,
    const int2* __restrict__ csre, const int* __restrict__ uidx,
    const int* __restrict__ pidx, float* __restrict__ out) {
    int tid = threadIdx.x;
    int b = blockIdx.x * 4 + (tid >> 6);
    if (b >= BATCH) return;
    int lane = tid & 63;
    int q2 = (lane >> 4) << 1;
    int t8 = (lane & 15) * 8;
    const char* xb = (const char*)x;
    int un = uidx[b], pn = NU + pidx[b];
    float u0, u1, u2, u3, p0, p1, p2, p3, ss, s;
    pull4(xb, csre, rowptr[un], rowptr[un + 1], q2, t8, u0, u1, u2, u3);
    ss = u0 * u0 + u1 * u1 + u2 * u2 + u3 * u3;
    for (int m = 8; m >= 1; m >>= 1) ss += __shfl_xor(ss, m, 64);
    s = 1.0f / fmaxf(sqrtf(ss), 1e-12f);
    u0 *= s; u1 *= s; u2 *= s; u3 *= s;
    pull4(xb, csre, rowptr[pn], rowptr[pn + 1], q2, t8, p0, p1, p2, p3);
    ss = p0 * p0 + p1 * p1 + p2 * p2 + p3 * p3;
    for (int m = 8; m >= 1; m >>= 1) ss += __shfl_xor(ss, m, 64);
    s = 1.0f / fmaxf(sqrtf(ss), 1e-12f);
    p0 *= s; p1 *= s; p2 *= s; p3 *= s;
    if ((lane >> 4) == 0)
        ((float4*)out)[b * 16 + (t8 >> 3)] = make_float4(u0, u1, u2, u3);
    float dot = u0 * p0 + u1 * p1 + u2 * p2 + u3 * p3;
    float uu = u0 * u0 + u1 * u1 + u2 * u2 + u3 * u3;
    float pp = p0 * p0 + p1 * p1 + p2 * p2 + p3 * p3;
    for (int m = 8; m >= 1; m >>= 1) {
        dot += __shfl_xor(dot, m, 64);
        uu  += __shfl_xor(uu, m, 64);
        pp  += __shfl_xor(pp, m, 64);
    }
    if (lane == 0) {
        float cs = dot / (fmaxf(sqrtf(uu), 1e-8f) * fmaxf(sqrtf(pp), 1e-8f));
        atomicAdd(out + BATCH * DD, (1.0f - cs) * (1.0f / BATCH));
    }
}

extern "C" void kernel_launch(void* const* d_in, const int* in_sizes, int n_in,
                              void* d_out, int out_size, void* d_ws, size_t ws_size,
                              hipStream_t stream) {
    const float* user_emb      = (const float*)d_in[0];
    const float* artist_emb    = (const float*)d_in[1];
    const float* album_emb     = (const float*)d_in[2];
    const float* item_audio    = (const float*)d_in[3];
    const float* adapter_W     = (const float*)d_in[4];
    const float* adapter_b     = (const float*)d_in[5];
    const float* mlp_W1        = (const float*)d_in[6];
    const float* mlp_b1        = (const float*)d_in[7];
    const float* mlp_W2        = (const float*)d_in[8];
    const float* mlp_b2        = (const float*)d_in[9];
    const float* edge_features = (const float*)d_in[10];
    const int*   edge_user     = (const int*)d_in[11];
    const int*   edge_item     = (const int*)d_in[12];
    const int*   artist_ids    = (const int*)d_in[13];
    const int*   album_ids     = (const int*)d_in[14];
    const int*   user_idx      = (const int*)d_in[15];
    const int*   pos_item_id   = (const int*)d_in[16];

    char* p = (char*)d_ws;
    unsigned short* XB0 = (unsigned short*)p; p += (size_t)NN * DD * 2;
    unsigned short* XB1 = (unsigned short*)p; p += (size_t)NN * DD * 2;
    float* W       = (float*)p; p += (size_t)E2 * 4;
    int2*  CSRE    = (int2*)p;  p += (size_t)4200000 * 8;   // padded CSR
    int*   EPOS    = (int*)p;   p += (size_t)E2 * 4;
    unsigned* DEGC = (unsigned*)p; p += (size_t)NN * 8;     // u32 used, u64 reserved
    float* DIS     = (float*)p; p += (size_t)NN * 4;
    int*   ROWPTR  = (int*)p;   p += (size_t)(NN + 1) * 4;
    int*   BSUM    = (int*)p;   p += (size_t)((NBLK1 + 3) & ~3) * 4;
    unsigned char* FLAGS = (unsigned char*)p; p += (size_t)NN;

    hipMemsetAsync(DEGC, 0, NN * sizeof(unsigned), stream);
    hipMemsetAsync(FLAGS, 0, NN, stream);
    hipMemsetAsync((float*)d_out + BATCH * DD, 0, sizeof(float), stream);

    k_prep<<<PREP_GRID, 256, 0, stream>>>(
        edge_features, mlp_W1, mlp_b1, mlp_W2, mlp_b2, edge_user, edge_item,
        W, DEGC, EPOS, item_audio, artist_emb, album_emb, artist_ids, album_ids,
        adapter_W, adapter_b, user_emb, XB0);

    k_scan_local<<<NBLK1, SCAN_CHUNK, 0, stream>>>(DEGC, ROWPTR, BSUM);
    k_scan_bsum<<<1, 512, 0, stream>>>(BSUM);
    k_scan_add_dis<<<(NN + 255) / 256, 256, 0, stream>>>(ROWPTR, BSUM, DEGC, DIS,
                                                         CSRE);
    k_fill<<<(E2 + 255) / 256, 256, 0, stream>>>(W, edge_user, edge_item, DIS,
                                                 ROWPTR, EPOS, CSRE);
    k_mark<<<(2 * BATCH + 255) / 256, 256, 0, stream>>>(user_idx, pos_item_id,
                                                        ROWPTR, CSRE, FLAGS);

    k_prop<false><<<(NN + 3) / 4, 256, 0, stream>>>(XB0, ROWPTR, CSRE, XB1, nullptr);
    k_prop<true><<<(NN + 3) / 4, 256, 0, stream>>>(XB1, ROWPTR, CSRE, XB0, FLAGS);

    k_tail<<<BATCH / 4, 256, 0, stream>>>(XB0, ROWPTR, CSRE, user_idx,
                                          pos_item_id, (float*)d_out);
}